// Round 7
// baseline (266.996 us; speedup 1.0000x reference)
//
#include <hip/hip_runtime.h>
#include <hip/hip_bf16.h>
#include <hip/hip_fp16.h>
#include <type_traits>

typedef _Float16 f16;
typedef __attribute__((ext_vector_type(8))) _Float16 f16x8;
typedef __attribute__((ext_vector_type(4))) float floatx4;

#define B_ 4
#define T_ 2048
#define D_ 1024

// ws layout (bytes); total need = 106,954,752
#define XB_OFF   0ul
#define WB_OFF   16777216ul
#define QKV_OFF  23068672ul
#define S_OFF    73400320ul
#define VT_OFF   0ul

// async global->LDS, 16B per lane; lds dest = wave-uniform base + lane*16
#define ASYNC16(gp, lp) \
    __builtin_amdgcn_global_load_lds((const __attribute__((address_space(1))) unsigned int*)(gp), \
                                     (__attribute__((address_space(3))) unsigned int*)(lp), 16, 0, 0)

template<int N> __device__ __forceinline__ void vmwait() {
    if constexpr (N == 0)      asm volatile("s_waitcnt vmcnt(0)" ::: "memory");
    else if constexpr (N == 4) asm volatile("s_waitcnt vmcnt(4)" ::: "memory");
    else if constexpr (N == 6) asm volatile("s_waitcnt vmcnt(6)" ::: "memory");
    else static_assert(N == 0, "unsupported vmcnt literal");
}
// R6: raw barrier ONLY — no sched_barrier(0). The pin was m141's regression:
// it blocked ds_read(p+1) ∥ MFMA(p) overlap, capping MfmaUtil at 28%.
// Safety without the pin: loads can't hoist above vmwait (asm memory clobber);
// ds_reads can't sink below global_load_lds (may-alias LDS store); DMA
// intrinsics keep issue order (side-effecting); cross-wave WAR still barriered.
#define BAR()  __builtin_amdgcn_s_barrier()

// ---------------- cast fp32 -> fp16 ----------------
__global__ __launch_bounds__(256) void cast_all(
    const float* __restrict__ x, const float* __restrict__ wq,
    const float* __restrict__ wk, const float* __restrict__ wv,
    f16* __restrict__ xb, f16* __restrict__ wb)
{
    long i = (long)blockIdx.x * 256 + threadIdx.x;
    const float4* src; f16* dst;
    if (i < 2097152L)            { src = (const float4*)x;  dst = xb; }
    else if (i < 2359296L)       { i -= 2097152L; src = (const float4*)wq; dst = wb; }
    else if (i < 2621440L)       { i -= 2359296L; src = (const float4*)wk; dst = wb + 1048576; }
    else                         { i -= 2621440L; src = (const float4*)wv; dst = wb + 2097152; }
    float4 v = src[i];
    union { f16 h[4]; uint2 u; } o;
    o.h[0] = (f16)v.x; o.h[1] = (f16)v.y; o.h[2] = (f16)v.z; o.h[3] = (f16)v.w;
    ((uint2*)dst)[i] = o.u;
}

// ======== 8-phase 256x256 NT GEMM (T2+T3+T4+T5), 512 threads, BK=64 ========
// 8 waves as 2(M)x4(N); wave tile 128x64; acc[8][4] 16x16 frags.
// LDS per buffer: A [2 half][2 kk][128 rows][32 f16] (16K f16) then B same.
// Slab swizzle per 128-row section (verified conflict-free):
//   stage: lane tid -> LDS (row=tid>>2, slab=tid&3), global slab (tid&3)^((tid>>3)&3)
//   read:  global slab kg lives in LDS slab kg^((lr>>1)&3)
// Schedule per K-tile u (4 phases, 2 barriers each):
//   p0: ds_read a[mh0](8) b[nh0](4) | stage A0(u+1)->nxt | BAR | MFMA q(0,0) | BAR
//   p1: ds_read b[nh1](4)           | stage A1(u+1)->nxt | BAR | MFMA q(0,1) | BAR
//   p2: ds_read a[mh1](8)           | stage B0(u+2)->cur | BAR | MFMA q(1,1) | BAR
//   p3:                             | stage B1(u+2)->cur | BAR | MFMA q(1,0) | vmcnt(4) | BAR
// Ledger: cur.B overwrite at p2/p3 safe (all B ds_reads retired by p1 bar);
//   nxt.A overwrite at p0/p1 safe (nxt last read at u-1.p2, barriers since);
//   end-of-u vmcnt(4) retires B(u+1)+A(u+1) (oldest 8 of 12), leaves B(u+2).
template <typename CT>
__global__ __launch_bounds__(512, 2) void gemm8_nt(
    const f16* __restrict__ A, int lda, long sA,
    const f16* __restrict__ B, int ldb, long sB,
    CT* __restrict__ C, int ldc, long sC,
    int K, float alpha)
{
    __shared__ f16 lds[2][32768];   // 128 KiB

    const int tid = threadIdx.x;
    const int m0 = blockIdx.y * 256;
    const int n0 = blockIdx.x * 256;
    const int bz = blockIdx.z;
    A += (long)bz * sA; B += (long)bz * sB; C += (long)bz * sC;

    const int w  = tid >> 6;        // 0..7
    const int l  = tid & 63;
    const int wm = w >> 2;          // 0..1
    const int wn = w & 3;           // 0..3
    const int lr = l & 15;
    const int kg = l >> 4;
    const int kx = kg ^ ((lr >> 1) & 3);

    floatx4 acc[8][4] = {};

    const int srow = tid >> 2;                       // 0..127
    const int gsl  = (tid & 3) ^ ((tid >> 3) & 3);
    const long ldaL = lda, ldbL = ldb;
    const f16* Ag = A + (long)(m0 + srow) * ldaL + gsl * 8;
    const f16* Bg = B + (long)(n0 + srow) * ldbL + gsl * 8;

    auto stA = [&](int buf, int h, int t) {          // stage A half h of K-tile t
        f16* d = &lds[buf][h * 8192 + w * 512];
        const f16* g = Ag + (long)(h * 128) * ldaL + t * 64;
        ASYNC16(g,      d);
        ASYNC16(g + 32, d + 4096);
    };
    auto stB = [&](int buf, int h, int t) {
        f16* d = &lds[buf][16384 + h * 8192 + w * 512];
        const f16* g = Bg + (long)(h * 128) * ldbL + t * 64;
        ASYNC16(g,      d);
        ASYNC16(g + 32, d + 4096);
    };

    const int NT = K >> 6;
    // prologue: tile0 (A0,A1,B0,B1) + tile1 B halves; leave B(1) in flight
    stA(0, 0, 0); stA(0, 1, 0); stB(0, 0, 0); stB(0, 1, 0);
    stB(1, 0, 1); stB(1, 1, 1);
    vmwait<4>();
    BAR();

    const int abase = wm * 8192;
    const int bbase = 16384 + (wn >> 1) * 8192 + (wn & 1) * 2048;  // +row-strip offset
    f16x8 af[2][4], bf0[2][2], bf1[2][2];

    for (int u = 0; u < NT; ++u) {
        const int cur = u & 1;
        const f16* Lc = lds[cur];

        // ---- p0: quadrant (mh0, nh0) ----
        #pragma unroll
        for (int kk = 0; kk < 2; kk++) {
            #pragma unroll
            for (int mi = 0; mi < 4; mi++)
                af[kk][mi] = *(const f16x8*)&Lc[abase + kk * 4096 + (mi * 16 + lr) * 32 + kx * 8];
            #pragma unroll
            for (int ni = 0; ni < 2; ni++)
                bf0[kk][ni] = *(const f16x8*)&Lc[bbase + kk * 4096 + (ni * 16 + lr) * 32 + kx * 8];
        }
        if (u + 1 < NT) stA(cur ^ 1, 0, u + 1);
        BAR();
        __builtin_amdgcn_s_setprio(1);
        #pragma unroll
        for (int kk = 0; kk < 2; kk++)
            #pragma unroll
            for (int mi = 0; mi < 4; mi++)
                #pragma unroll
                for (int ni = 0; ni < 2; ni++)
                    acc[mi][ni] = __builtin_amdgcn_mfma_f32_16x16x32_f16(af[kk][mi], bf0[kk][ni], acc[mi][ni], 0, 0, 0);
        __builtin_amdgcn_s_setprio(0);
        BAR();

        // ---- p1: quadrant (mh0, nh1) ----
        #pragma unroll
        for (int kk = 0; kk < 2; kk++)
            #pragma unroll
            for (int ni = 0; ni < 2; ni++)
                bf1[kk][ni] = *(const f16x8*)&Lc[bbase + kk * 4096 + ((ni + 2) * 16 + lr) * 32 + kx * 8];
        if (u + 1 < NT) stA(cur ^ 1, 1, u + 1);
        BAR();
        __builtin_amdgcn_s_setprio(1);
        #pragma unroll
        for (int kk = 0; kk < 2; kk++)
            #pragma unroll
            for (int mi = 0; mi < 4; mi++)
                #pragma unroll
                for (int ni = 0; ni < 2; ni++)
                    acc[mi][ni + 2] = __builtin_amdgcn_mfma_f32_16x16x32_f16(af[kk][mi], bf1[kk][ni], acc[mi][ni + 2], 0, 0, 0);
        __builtin_amdgcn_s_setprio(0);
        BAR();

        // ---- p2: quadrant (mh1, nh1) ----
        #pragma unroll
        for (int kk = 0; kk < 2; kk++)
            #pragma unroll
            for (int mi = 0; mi < 4; mi++)
                af[kk][mi] = *(const f16x8*)&Lc[abase + kk * 4096 + ((mi + 4) * 16 + lr) * 32 + kx * 8];
        if (u + 2 < NT) stB(cur, 0, u + 2);
        BAR();
        __builtin_amdgcn_s_setprio(1);
        #pragma unroll
        for (int kk = 0; kk < 2; kk++)
            #pragma unroll
            for (int mi = 0; mi < 4; mi++)
                #pragma unroll
                for (int ni = 0; ni < 2; ni++)
                    acc[mi + 4][ni + 2] = __builtin_amdgcn_mfma_f32_16x16x32_f16(af[kk][mi], bf1[kk][ni], acc[mi + 4][ni + 2], 0, 0, 0);
        __builtin_amdgcn_s_setprio(0);
        BAR();

        // ---- p3: quadrant (mh1, nh0) ----
        if (u + 2 < NT) stB(cur, 1, u + 2);
        BAR();
        __builtin_amdgcn_s_setprio(1);
        #pragma unroll
        for (int kk = 0; kk < 2; kk++)
            #pragma unroll
            for (int mi = 0; mi < 4; mi++)
                #pragma unroll
                for (int ni = 0; ni < 2; ni++)
                    acc[mi + 4][ni] = __builtin_amdgcn_mfma_f32_16x16x32_f16(af[kk][mi], bf0[kk][ni], acc[mi + 4][ni], 0, 0, 0);
        __builtin_amdgcn_s_setprio(0);
        if (u + 2 < NT)      vmwait<4>();
        else if (u + 1 < NT) vmwait<0>();
        BAR();
    }

    // epilogue: C/D layout: col = lane&15, row = (lane>>4)*4 + reg
    #pragma unroll
    for (int mi = 0; mi < 8; mi++)
        #pragma unroll
        for (int ni = 0; ni < 4; ni++)
            #pragma unroll
            for (int r = 0; r < 4; r++) {
                int row = m0 + wm * 128 + mi * 16 + kg * 4 + r;
                int col = n0 + wn * 64 + ni * 16 + lr;
                float v = acc[mi][ni][r] * alpha;
                if constexpr (std::is_same<CT, float>::value)
                    C[(long)row * ldc + col] = v;
                else
                    C[(long)row * ldc + col] = (f16)v;
            }
}

// ---------------- NT GEMM 128x128 (3-buffer counted-vmcnt, pin removed) ----------------
template <typename CT, int BN, int WN>
__global__ __launch_bounds__(256, 3) void gemm_nt(
    const f16* __restrict__ A, int lda, long sA,
    const f16* __restrict__ B, int ldb, long sB,
    CT* __restrict__ C, int ldc, long sC,
    int K, float alpha)
{
    __shared__ f16 As[3][128 * 32];
    __shared__ f16 Bs[3][BN * 32];
    constexpr int L = 2 + BN / 64;

    const int tid = threadIdx.x;
    const int m0 = blockIdx.y * 128;
    const int n0 = blockIdx.x * BN;
    const int bz = blockIdx.z;
    A += (long)bz * sA;
    B += (long)bz * sB;
    C += (long)bz * sC;

    const int w  = tid >> 6;
    const int l  = tid & 63;
    const int wm = (w >> 1) * 64;
    const int wn = (w & 1) * WN;
    const int lr = l & 15;
    const int kg = l >> 4;
    const int kx = kg ^ ((lr >> 1) & 3);

    constexpr int NI = WN / 16;
    floatx4 acc[4][NI] = {};

    const int srow = tid >> 2;
    const int gsl  = (tid & 3) ^ ((tid >> 3) & 3);
    const long ldaL = lda, ldbL = ldb;
    const f16* Aptr = A + (long)(m0 + srow) * ldaL + gsl * 8;
    const f16* Bptr = B + (long)(n0 + srow) * ldbL + gsl * 8;

    auto stage = [&](f16* Ad, f16* Bd, int kk) {
        #pragma unroll
        for (int rh = 0; rh < 2; rh++)
            ASYNC16(Aptr + kk + rh * 64 * ldaL, Ad + rh * 2048 + w * 512);
        #pragma unroll
        for (int rh = 0; rh < BN / 64; rh++)
            ASYNC16(Bptr + kk + rh * 64 * ldbL, Bd + rh * 2048 + w * 512);
    };

    f16 *a0 = As[0], *a1 = As[1], *a2 = As[2];
    f16 *b0 = Bs[0], *b1 = Bs[1], *b2 = Bs[2];

    const int NT = K >> 5;
    stage(a0, b0, 0);
    stage(a1, b1, 32);

    for (int t = 0; t < NT; ++t) {
        if (t < NT - 1) vmwait<L>(); else vmwait<0>();
        __builtin_amdgcn_s_barrier();

        if (t + 2 < NT) stage(a2, b2, (t + 2) << 5);

        f16x8 af[4], bf[NI];
        #pragma unroll
        for (int mi = 0; mi < 4; mi++)
            af[mi] = *(const f16x8*)&a0[(wm + mi * 16 + lr) * 32 + kx * 8];
        #pragma unroll
        for (int ni = 0; ni < NI; ni++)
            bf[ni] = *(const f16x8*)&b0[(wn + ni * 16 + lr) * 32 + kx * 8];
        #pragma unroll
        for (int mi = 0; mi < 4; mi++)
            #pragma unroll
            for (int ni = 0; ni < NI; ni++)
                acc[mi][ni] = __builtin_amdgcn_mfma_f32_16x16x32_f16(af[mi], bf[ni], acc[mi][ni], 0, 0, 0);

        f16* ta = a0; a0 = a1; a1 = a2; a2 = ta;
        f16* tb = b0; b0 = b1; b1 = b2; b2 = tb;
    }

    #pragma unroll
    for (int mi = 0; mi < 4; mi++) {
        #pragma unroll
        for (int ni = 0; ni < NI; ni++) {
            #pragma unroll
            for (int r = 0; r < 4; r++) {
                int row = m0 + wm + mi * 16 + kg * 4 + r;
                int col = n0 + wn + ni * 16 + lr;
                float v = acc[mi][ni][r] * alpha;
                if constexpr (std::is_same<CT, float>::value)
                    C[(long)row * ldc + col] = v;
                else
                    C[(long)row * ldc + col] = (f16)v;
            }
        }
    }
}

// ---------------- transpose V -> Vt[b][d][j] ----------------
__global__ __launch_bounds__(256) void transpose_v(const f16* __restrict__ qkv, f16* __restrict__ vt)
{
    __shared__ f16 tile[32][33];
    int b  = blockIdx.z;
    int j0 = blockIdx.x * 32;
    int d0 = blockIdx.y * 32;
    int tx = threadIdx.x & 31;
    int ty = threadIdx.x >> 5;
    #pragma unroll
    for (int i = 0; i < 4; i++) {
        int j = j0 + ty + i * 8;
        tile[ty + i * 8][tx] = qkv[((long)b * T_ + j) * 3072 + 2048 + d0 + tx];
    }
    __syncthreads();
    #pragma unroll
    for (int i = 0; i < 4; i++) {
        int d = d0 + ty + i * 8;
        vt[((long)b * D_ + d) * T_ + j0 + tx] = tile[tx][ty + i * 8];
    }
}

// ---------------- row softmax ----------------
__global__ __launch_bounds__(256) void softmax_rows(f16* __restrict__ S)
{
    long row = (long)blockIdx.x * 4 + (threadIdx.x >> 6);
    int l = threadIdx.x & 63;
    uint4* p4 = (uint4*)(S + row * 2048);
    union U { uint4 u; f16 h[8]; } d[4];
    float v[32];
    float mx = -1e30f;
    #pragma unroll
    for (int i = 0; i < 4; i++) {
        d[i].u = p4[i * 64 + l];
        #pragma unroll
        for (int j = 0; j < 8; j++) { v[i * 8 + j] = (float)d[i].h[j]; mx = fmaxf(mx, v[i * 8 + j]); }
    }
    #pragma unroll
    for (int off = 32; off; off >>= 1) mx = fmaxf(mx, __shfl_xor(mx, off, 64));
    float s = 0.f;
    #pragma unroll
    for (int i = 0; i < 32; i++) { v[i] = __expf(v[i] - mx); s += v[i]; }
    #pragma unroll
    for (int off = 32; off; off >>= 1) s += __shfl_xor(s, off, 64);
    float inv = 1.f / s;
    #pragma unroll
    for (int i = 0; i < 4; i++) {
        #pragma unroll
        for (int j = 0; j < 8; j++) d[i].h[j] = (f16)(v[i * 8 + j] * inv);
        p4[i * 64 + l] = d[i].u;
    }
}

// ---------------- launch ----------------
extern "C" void kernel_launch(void* const* d_in, const int* in_sizes, int n_in,
                              void* d_out, int out_size, void* d_ws, size_t ws_size,
                              hipStream_t stream)
{
    const float* x  = (const float*)d_in[0];
    const float* wq = (const float*)d_in[1];
    const float* wk = (const float*)d_in[2];
    const float* wv = (const float*)d_in[3];
    float* out = (float*)d_out;
    char* ws = (char*)d_ws;
    f16* xb  = (f16*)(ws + XB_OFF);
    f16* wb  = (f16*)(ws + WB_OFF);
    f16* qkv = (f16*)(ws + QKV_OFF);
    f16* s   = (f16*)(ws + S_OFF);
    f16* vt  = (f16*)(ws + VT_OFF);

    // 1) cast
    cast_all<<<11264, 256, 0, stream>>>(x, wq, wk, wv, xb, wb);

    // 2) QKV = xb @ Wb^T : M=8192, N=3072, K=1024 (8-phase 256^2)
    gemm8_nt<f16><<<dim3(12, 32, 1), 512, 0, stream>>>(
        xb, 1024, 0L, wb, 1024, 0L, qkv, 3072, 0L, 1024, 1.0f);

    // 3) Vt
    transpose_v<<<dim3(64, 32, 4), 256, 0, stream>>>(qkv, vt);

    // 4) S = (1/32) Q @ K^T per batch : M=N=2048, K=1024 (8-phase 256^2)
    gemm8_nt<f16><<<dim3(8, 8, 4), 512, 0, stream>>>(
        qkv,        3072, (long)T_ * 3072,
        qkv + 1024, 3072, (long)T_ * 3072,
        s,          2048, (long)T_ * 2048, 1024, 0.03125f);

    // 5) softmax
    softmax_rows<<<2048, 256, 0, stream>>>(s);

    // 6) O = P @ Vt^T per batch : M=2048, N=1024, K=2048 (128-tile)
    gemm_nt<float, 128, 64><<<dim3(8, 16, 4), 256, 0, stream>>>(
        s,  2048, (long)T_ * 2048,
        vt, 2048, (long)D_ * 2048,
        out, 1024, (long)T_ * 1024, 2048, 1.0f);
}

// Round 8
// 260.606 us; speedup vs baseline: 1.0245x; 1.0245x over previous
//
#include <hip/hip_runtime.h>
#include <hip/hip_bf16.h>
#include <hip/hip_fp16.h>
#include <type_traits>

typedef _Float16 f16;
typedef __attribute__((ext_vector_type(8))) _Float16 f16x8;
typedef __attribute__((ext_vector_type(4))) float floatx4;

#define B_ 4
#define T_ 2048
#define D_ 1024

// ws layout (bytes); total need = 106,954,752
#define XB_OFF   0ul
#define WB_OFF   16777216ul
#define QKV_OFF  23068672ul
#define S_OFF    73400320ul
#define VT_OFF   0ul

// async global->LDS, 16B per lane; lds dest = wave-uniform base + lane*16
#define ASYNC16(gp, lp) \
    __builtin_amdgcn_global_load_lds((const __attribute__((address_space(1))) unsigned int*)(gp), \
                                     (__attribute__((address_space(3))) unsigned int*)(lp), 16, 0, 0)

template<int N> __device__ __forceinline__ void vmwait() {
    if constexpr (N == 0)      asm volatile("s_waitcnt vmcnt(0)" ::: "memory");
    else if constexpr (N == 4) asm volatile("s_waitcnt vmcnt(4)" ::: "memory");
    else if constexpr (N == 6) asm volatile("s_waitcnt vmcnt(6)" ::: "memory");
    else static_assert(N == 0, "unsupported vmcnt literal");
}
#define BAR()  __builtin_amdgcn_s_barrier()

// ---------------- cast fp32 -> fp16 ----------------
__global__ __launch_bounds__(256) void cast_all(
    const float* __restrict__ x, const float* __restrict__ wq,
    const float* __restrict__ wk, const float* __restrict__ wv,
    f16* __restrict__ xb, f16* __restrict__ wb)
{
    long i = (long)blockIdx.x * 256 + threadIdx.x;
    const float4* src; f16* dst;
    if (i < 2097152L)            { src = (const float4*)x;  dst = xb; }
    else if (i < 2359296L)       { i -= 2097152L; src = (const float4*)wq; dst = wb; }
    else if (i < 2621440L)       { i -= 2359296L; src = (const float4*)wk; dst = wb + 1048576; }
    else                         { i -= 2621440L; src = (const float4*)wv; dst = wb + 2097152; }
    float4 v = src[i];
    union { f16 h[4]; uint2 u; } o;
    o.h[0] = (f16)v.x; o.h[1] = (f16)v.y; o.h[2] = (f16)v.z; o.h[3] = (f16)v.w;
    ((uint2*)dst)[i] = o.u;
}

// ======== 8-phase 256x256 NT GEMM (T2+T3+T4+T5), 512 threads, BK=64 ========
// (verified passing R6/R7; TAG only distinguishes QKV/S in profiles)
// 8 waves as 2(M)x4(N); wave tile 128x64; acc[8][4] 16x16 frags.
// Schedule per K-tile u (4 phases): see ledger in R5/R6 notes.
template <typename CT, int TAG>
__global__ __launch_bounds__(512, 2) void gemm8_nt(
    const f16* __restrict__ A, int lda, long sA,
    const f16* __restrict__ B, int ldb, long sB,
    CT* __restrict__ C, int ldc, long sC,
    int K, float alpha)
{
    __shared__ f16 lds[2][32768];   // 128 KiB

    const int tid = threadIdx.x;
    const int m0 = blockIdx.y * 256;
    const int n0 = blockIdx.x * 256;
    const int bz = blockIdx.z;
    A += (long)bz * sA; B += (long)bz * sB; C += (long)bz * sC;

    const int w  = tid >> 6;        // 0..7
    const int l  = tid & 63;
    const int wm = w >> 2;          // 0..1
    const int wn = w & 3;           // 0..3
    const int lr = l & 15;
    const int kg = l >> 4;
    const int kx = kg ^ ((lr >> 1) & 3);

    floatx4 acc[8][4] = {};

    const int srow = tid >> 2;                       // 0..127
    const int gsl  = (tid & 3) ^ ((tid >> 3) & 3);
    const long ldaL = lda, ldbL = ldb;
    const f16* Ag = A + (long)(m0 + srow) * ldaL + gsl * 8;
    const f16* Bg = B + (long)(n0 + srow) * ldbL + gsl * 8;

    auto stA = [&](int buf, int h, int t) {
        f16* d = &lds[buf][h * 8192 + w * 512];
        const f16* g = Ag + (long)(h * 128) * ldaL + t * 64;
        ASYNC16(g,      d);
        ASYNC16(g + 32, d + 4096);
    };
    auto stB = [&](int buf, int h, int t) {
        f16* d = &lds[buf][16384 + h * 8192 + w * 512];
        const f16* g = Bg + (long)(h * 128) * ldbL + t * 64;
        ASYNC16(g,      d);
        ASYNC16(g + 32, d + 4096);
    };

    const int NT = K >> 6;
    stA(0, 0, 0); stA(0, 1, 0); stB(0, 0, 0); stB(0, 1, 0);
    stB(1, 0, 1); stB(1, 1, 1);
    vmwait<4>();
    BAR();

    const int abase = wm * 8192;
    const int bbase = 16384 + (wn >> 1) * 8192 + (wn & 1) * 2048;
    f16x8 af[2][4], bf0[2][2], bf1[2][2];

    for (int u = 0; u < NT; ++u) {
        const int cur = u & 1;
        const f16* Lc = lds[cur];

        // p0: quadrant (mh0, nh0)
        #pragma unroll
        for (int kk = 0; kk < 2; kk++) {
            #pragma unroll
            for (int mi = 0; mi < 4; mi++)
                af[kk][mi] = *(const f16x8*)&Lc[abase + kk * 4096 + (mi * 16 + lr) * 32 + kx * 8];
            #pragma unroll
            for (int ni = 0; ni < 2; ni++)
                bf0[kk][ni] = *(const f16x8*)&Lc[bbase + kk * 4096 + (ni * 16 + lr) * 32 + kx * 8];
        }
        if (u + 1 < NT) stA(cur ^ 1, 0, u + 1);
        BAR();
        __builtin_amdgcn_s_setprio(1);
        #pragma unroll
        for (int kk = 0; kk < 2; kk++)
            #pragma unroll
            for (int mi = 0; mi < 4; mi++)
                #pragma unroll
                for (int ni = 0; ni < 2; ni++)
                    acc[mi][ni] = __builtin_amdgcn_mfma_f32_16x16x32_f16(af[kk][mi], bf0[kk][ni], acc[mi][ni], 0, 0, 0);
        __builtin_amdgcn_s_setprio(0);
        BAR();

        // p1: quadrant (mh0, nh1)
        #pragma unroll
        for (int kk = 0; kk < 2; kk++)
            #pragma unroll
            for (int ni = 0; ni < 2; ni++)
                bf1[kk][ni] = *(const f16x8*)&Lc[bbase + kk * 4096 + ((ni + 2) * 16 + lr) * 32 + kx * 8];
        if (u + 1 < NT) stA(cur ^ 1, 1, u + 1);
        BAR();
        __builtin_amdgcn_s_setprio(1);
        #pragma unroll
        for (int kk = 0; kk < 2; kk++)
            #pragma unroll
            for (int mi = 0; mi < 4; mi++)
                #pragma unroll
                for (int ni = 0; ni < 2; ni++)
                    acc[mi][ni + 2] = __builtin_amdgcn_mfma_f32_16x16x32_f16(af[kk][mi], bf1[kk][ni], acc[mi][ni + 2], 0, 0, 0);
        __builtin_amdgcn_s_setprio(0);
        BAR();

        // p2: quadrant (mh1, nh1)
        #pragma unroll
        for (int kk = 0; kk < 2; kk++)
            #pragma unroll
            for (int mi = 0; mi < 4; mi++)
                af[kk][mi] = *(const f16x8*)&Lc[abase + kk * 4096 + ((mi + 4) * 16 + lr) * 32 + kx * 8];
        if (u + 2 < NT) stB(cur, 0, u + 2);
        BAR();
        __builtin_amdgcn_s_setprio(1);
        #pragma unroll
        for (int kk = 0; kk < 2; kk++)
            #pragma unroll
            for (int mi = 0; mi < 4; mi++)
                #pragma unroll
                for (int ni = 0; ni < 2; ni++)
                    acc[mi + 4][ni + 2] = __builtin_amdgcn_mfma_f32_16x16x32_f16(af[kk][mi], bf1[kk][ni], acc[mi + 4][ni + 2], 0, 0, 0);
        __builtin_amdgcn_s_setprio(0);
        BAR();

        // p3: quadrant (mh1, nh0)
        if (u + 2 < NT) stB(cur, 1, u + 2);
        BAR();
        __builtin_amdgcn_s_setprio(1);
        #pragma unroll
        for (int kk = 0; kk < 2; kk++)
            #pragma unroll
            for (int mi = 0; mi < 4; mi++)
                #pragma unroll
                for (int ni = 0; ni < 2; ni++)
                    acc[mi + 4][ni] = __builtin_amdgcn_mfma_f32_16x16x32_f16(af[kk][mi], bf0[kk][ni], acc[mi + 4][ni], 0, 0, 0);
        __builtin_amdgcn_s_setprio(0);
        if (u + 2 < NT)      vmwait<4>();
        else if (u + 1 < NT) vmwait<0>();
        BAR();
    }

    #pragma unroll
    for (int mi = 0; mi < 8; mi++)
        #pragma unroll
        for (int ni = 0; ni < 4; ni++)
            #pragma unroll
            for (int r = 0; r < 4; r++) {
                int row = m0 + wm * 128 + mi * 16 + kg * 4 + r;
                int col = n0 + wn * 64 + ni * 16 + lr;
                float v = acc[mi][ni][r] * alpha;
                if constexpr (std::is_same<CT, float>::value)
                    C[(long)row * ldc + col] = v;
                else
                    C[(long)row * ldc + col] = (f16)v;
            }
}

// ======== 8-phase 128x256 NT GEMM (R8 new, for PV: exact 256-block grid) ========
// 8 waves as 2(M)x4(N); wave tile 64x64; acc[4][4]; LDS 96 KiB (A 16K f16, B 32K f16 per buf).
// Layout per buffer: A [kk][128 rows][32], B at +8192: [kk][256 rows][32]; same slab swizzle
// (row bases all ≡0 mod 8 -> conflict-free relation preserved).
// Per K-tile u: p0{ds af0(4)+bf0(4) | stA kk0(u+1)->nxt | BAR | 8 MFMA | BAR}
//               p1{ds bf1(4)        | stA kk1(u+1)->nxt | BAR | 8 MFMA | BAR}
//               p2{ds af1(4)        | stB kk0(u+2)->cur | BAR | 8 MFMA | BAR}
//               p3{                 | stB kk1(u+2)->cur | BAR | 8 MFMA | vmcnt | BAR}
// Queue at p3 wait: [B(u+1)x4, A(u+1)x2, B(u+2)x4] -> vmcnt(4) retires tile-u+1 data.
// Prologue: stA0,stA1,stB0,stB1(tile0)=6 + stB(1)=4 -> 10; vmcnt(4) -> tile0 ready, B(1) in flight.
// B-overwrite safe: all B ds_reads retire by p1's closing barrier (bf0 p0, bf1 p1).
template <typename CT>
__global__ __launch_bounds__(512, 2) void gemm8b_nt(
    const f16* __restrict__ A, int lda, long sA,
    const f16* __restrict__ B, int ldb, long sB,
    CT* __restrict__ C, int ldc, long sC,
    int K, float alpha)
{
    __shared__ f16 lds[2][24576];   // 96 KiB

    const int tid = threadIdx.x;
    const int m0 = blockIdx.y * 128;
    const int n0 = blockIdx.x * 256;
    const int bz = blockIdx.z;
    A += (long)bz * sA; B += (long)bz * sB; C += (long)bz * sC;

    const int w  = tid >> 6;        // 0..7
    const int l  = tid & 63;
    const int wm = w >> 2;          // 0..1 (M halves of 128 -> 64 rows each)
    const int wn = w & 3;           // 0..3 (N quarters of 256 -> 64 each)
    const int lr = l & 15;
    const int kg = l >> 4;
    const int kx = kg ^ ((lr >> 1) & 3);

    floatx4 acc[4][4] = {};

    const int srow = tid >> 2;                       // 0..127
    const int gsl  = (tid & 3) ^ ((tid >> 3) & 3);
    const long ldaL = lda, ldbL = ldb;
    const f16* Ag = A + (long)(m0 + srow) * ldaL + gsl * 8;
    const f16* Bg = B + (long)(n0 + srow) * ldbL + gsl * 8;

    auto stA = [&](int buf, int kk, int t) {         // 1 ASYNC16: A kk-section (128x32)
        ASYNC16(Ag + kk * 32 + t * 64, &lds[buf][kk * 4096 + w * 512]);
    };
    auto stB = [&](int buf, int kk, int t) {         // 2 ASYNC16: B kk-section (256x32)
        const f16* g = Bg + kk * 32 + t * 64;
        f16* d = &lds[buf][8192 + kk * 8192 + w * 512];
        ASYNC16(g,                   d);
        ASYNC16(g + 128 * ldbL,      d + 4096);
    };

    const int NT = K >> 6;
    stA(0, 0, 0); stA(0, 1, 0); stB(0, 0, 0); stB(0, 1, 0);
    stB(1, 0, 1); stB(1, 1, 1);
    vmwait<4>();
    BAR();

    const int arow = wm * 64;      // wave's A row base
    const int brow = wn * 64;      // wave's B row base
    f16x8 af0[2][2], af1[2][2], bf0[2][2], bf1[2][2];

    for (int u = 0; u < NT; ++u) {
        const int cur = u & 1;
        const f16* Lc = lds[cur];

        // p0: (mi01, ni01)
        #pragma unroll
        for (int kk = 0; kk < 2; kk++) {
            #pragma unroll
            for (int mi = 0; mi < 2; mi++)
                af0[kk][mi] = *(const f16x8*)&Lc[kk * 4096 + (arow + mi * 16 + lr) * 32 + kx * 8];
            #pragma unroll
            for (int ni = 0; ni < 2; ni++)
                bf0[kk][ni] = *(const f16x8*)&Lc[8192 + kk * 8192 + (brow + ni * 16 + lr) * 32 + kx * 8];
        }
        if (u + 1 < NT) stA(cur ^ 1, 0, u + 1);
        BAR();
        __builtin_amdgcn_s_setprio(1);
        #pragma unroll
        for (int kk = 0; kk < 2; kk++)
            #pragma unroll
            for (int mi = 0; mi < 2; mi++)
                #pragma unroll
                for (int ni = 0; ni < 2; ni++)
                    acc[mi][ni] = __builtin_amdgcn_mfma_f32_16x16x32_f16(af0[kk][mi], bf0[kk][ni], acc[mi][ni], 0, 0, 0);
        __builtin_amdgcn_s_setprio(0);
        BAR();

        // p1: (mi01, ni23)
        #pragma unroll
        for (int kk = 0; kk < 2; kk++)
            #pragma unroll
            for (int ni = 0; ni < 2; ni++)
                bf1[kk][ni] = *(const f16x8*)&Lc[8192 + kk * 8192 + (brow + (ni + 2) * 16 + lr) * 32 + kx * 8];
        if (u + 1 < NT) stA(cur ^ 1, 1, u + 1);
        BAR();
        __builtin_amdgcn_s_setprio(1);
        #pragma unroll
        for (int kk = 0; kk < 2; kk++)
            #pragma unroll
            for (int mi = 0; mi < 2; mi++)
                #pragma unroll
                for (int ni = 0; ni < 2; ni++)
                    acc[mi][ni + 2] = __builtin_amdgcn_mfma_f32_16x16x32_f16(af0[kk][mi], bf1[kk][ni], acc[mi][ni + 2], 0, 0, 0);
        __builtin_amdgcn_s_setprio(0);
        BAR();

        // p2: (mi23, ni23)
        #pragma unroll
        for (int kk = 0; kk < 2; kk++)
            #pragma unroll
            for (int mi = 0; mi < 2; mi++)
                af1[kk][mi] = *(const f16x8*)&Lc[kk * 4096 + (arow + (mi + 2) * 16 + lr) * 32 + kx * 8];
        if (u + 2 < NT) stB(cur, 0, u + 2);
        BAR();
        __builtin_amdgcn_s_setprio(1);
        #pragma unroll
        for (int kk = 0; kk < 2; kk++)
            #pragma unroll
            for (int mi = 0; mi < 2; mi++)
                #pragma unroll
                for (int ni = 0; ni < 2; ni++)
                    acc[mi + 2][ni + 2] = __builtin_amdgcn_mfma_f32_16x16x32_f16(af1[kk][mi], bf1[kk][ni], acc[mi + 2][ni + 2], 0, 0, 0);
        __builtin_amdgcn_s_setprio(0);
        BAR();

        // p3: (mi23, ni01)
        if (u + 2 < NT) stB(cur, 1, u + 2);
        BAR();
        __builtin_amdgcn_s_setprio(1);
        #pragma unroll
        for (int kk = 0; kk < 2; kk++)
            #pragma unroll
            for (int mi = 0; mi < 2; mi++)
                #pragma unroll
                for (int ni = 0; ni < 2; ni++)
                    acc[mi + 2][ni] = __builtin_amdgcn_mfma_f32_16x16x32_f16(af1[kk][mi], bf0[kk][ni], acc[mi + 2][ni], 0, 0, 0);
        __builtin_amdgcn_s_setprio(0);
        if (u + 2 < NT)      vmwait<4>();
        else if (u + 1 < NT) vmwait<0>();
        BAR();
    }

    #pragma unroll
    for (int mi = 0; mi < 4; mi++)
        #pragma unroll
        for (int ni = 0; ni < 4; ni++)
            #pragma unroll
            for (int r = 0; r < 4; r++) {
                int row = m0 + wm * 64 + mi * 16 + kg * 4 + r;
                int col = n0 + wn * 64 + ni * 16 + lr;
                float v = acc[mi][ni][r] * alpha;
                if constexpr (std::is_same<CT, float>::value)
                    C[(long)row * ldc + col] = v;
                else
                    C[(long)row * ldc + col] = (f16)v;
            }
}

// ---------------- transpose V -> Vt[b][d][j] ----------------
__global__ __launch_bounds__(256) void transpose_v(const f16* __restrict__ qkv, f16* __restrict__ vt)
{
    __shared__ f16 tile[32][33];
    int b  = blockIdx.z;
    int j0 = blockIdx.x * 32;
    int d0 = blockIdx.y * 32;
    int tx = threadIdx.x & 31;
    int ty = threadIdx.x >> 5;
    #pragma unroll
    for (int i = 0; i < 4; i++) {
        int j = j0 + ty + i * 8;
        tile[ty + i * 8][tx] = qkv[((long)b * T_ + j) * 3072 + 2048 + d0 + tx];
    }
    __syncthreads();
    #pragma unroll
    for (int i = 0; i < 4; i++) {
        int d = d0 + ty + i * 8;
        vt[((long)b * D_ + d) * T_ + j0 + tx] = tile[tx][ty + i * 8];
    }
}

// ---------------- row softmax ----------------
__global__ __launch_bounds__(256) void softmax_rows(f16* __restrict__ S)
{
    long row = (long)blockIdx.x * 4 + (threadIdx.x >> 6);
    int l = threadIdx.x & 63;
    uint4* p4 = (uint4*)(S + row * 2048);
    union U { uint4 u; f16 h[8]; } d[4];
    float v[32];
    float mx = -1e30f;
    #pragma unroll
    for (int i = 0; i < 4; i++) {
        d[i].u = p4[i * 64 + l];
        #pragma unroll
        for (int j = 0; j < 8; j++) { v[i * 8 + j] = (float)d[i].h[j]; mx = fmaxf(mx, v[i * 8 + j]); }
    }
    #pragma unroll
    for (int off = 32; off; off >>= 1) mx = fmaxf(mx, __shfl_xor(mx, off, 64));
    float s = 0.f;
    #pragma unroll
    for (int i = 0; i < 32; i++) { v[i] = __expf(v[i] - mx); s += v[i]; }
    #pragma unroll
    for (int off = 32; off; off >>= 1) s += __shfl_xor(s, off, 64);
    float inv = 1.f / s;
    #pragma unroll
    for (int i = 0; i < 4; i++) {
        #pragma unroll
        for (int j = 0; j < 8; j++) d[i].h[j] = (f16)(v[i * 8 + j] * inv);
        p4[i * 64 + l] = d[i].u;
    }
}

// ---------------- launch ----------------
extern "C" void kernel_launch(void* const* d_in, const int* in_sizes, int n_in,
                              void* d_out, int out_size, void* d_ws, size_t ws_size,
                              hipStream_t stream)
{
    const float* x  = (const float*)d_in[0];
    const float* wq = (const float*)d_in[1];
    const float* wk = (const float*)d_in[2];
    const float* wv = (const float*)d_in[3];
    float* out = (float*)d_out;
    char* ws = (char*)d_ws;
    f16* xb  = (f16*)(ws + XB_OFF);
    f16* wb  = (f16*)(ws + WB_OFF);
    f16* qkv = (f16*)(ws + QKV_OFF);
    f16* s   = (f16*)(ws + S_OFF);
    f16* vt  = (f16*)(ws + VT_OFF);

    // 1) cast
    cast_all<<<11264, 256, 0, stream>>>(x, wq, wk, wv, xb, wb);

    // 2) QKV = xb @ Wb^T : M=8192, N=3072, K=1024 (8-phase 256^2, TAG 0)
    gemm8_nt<f16, 0><<<dim3(12, 32, 1), 512, 0, stream>>>(
        xb, 1024, 0L, wb, 1024, 0L, qkv, 3072, 0L, 1024, 1.0f);

    // 3) Vt
    transpose_v<<<dim3(64, 32, 4), 256, 0, stream>>>(qkv, vt);

    // 4) S = (1/32) Q @ K^T per batch : M=N=2048, K=1024 (8-phase 256^2, TAG 1)
    gemm8_nt<f16, 1><<<dim3(8, 8, 4), 512, 0, stream>>>(
        qkv,        3072, (long)T_ * 3072,
        qkv + 1024, 3072, (long)T_ * 3072,
        s,          2048, (long)T_ * 2048, 1024, 0.03125f);

    // 5) softmax
    softmax_rows<<<2048, 256, 0, stream>>>(s);

    // 6) O = P @ Vt^T per batch : M=2048, N=1024, K=2048
    //    R8: 8-phase 128x256 variant -> grid (4,16,4) = 256 blocks exactly, 1/CU, no tail
    gemm8b_nt<float><<<dim3(4, 16, 4), 512, 0, stream>>>(
        s,  2048, (long)T_ * 2048,
        vt, 2048, (long)D_ * 2048,
        out, 1024, (long)T_ * 1024, 2048, 1.0f);
}

// Round 9
// 251.463 us; speedup vs baseline: 1.0618x; 1.0364x over previous
//
#include <hip/hip_runtime.h>
#include <hip/hip_bf16.h>
#include <hip/hip_fp16.h>
#include <type_traits>

typedef _Float16 f16;
typedef __attribute__((ext_vector_type(8))) _Float16 f16x8;
typedef __attribute__((ext_vector_type(4))) float floatx4;

#define B_ 4
#define T_ 2048
#define D_ 1024

// ws layout (bytes); total = 106,954,752 (unchanged budget)
#define XB_OFF   0ul          // f16 x: 16 MB
#define WB_OFF   16777216ul   // f16 [Wq;Wk;Wv] 3072x1024: 6 MB
#define QK_OFF   23068672ul   // f16 qk (8192x2048, packed Q|K): 32 MB
#define VT_OFF   56623104ul   // f16 vt (4x1024x2048): 16 MB  (own region: written while xb is read)
#define S_OFF    73400320ul   // f16 S (4x2048x2048): 32 MB

// async global->LDS, 16B per lane; lds dest = wave-uniform base + lane*16
#define ASYNC16(gp, lp) \
    __builtin_amdgcn_global_load_lds((const __attribute__((address_space(1))) unsigned int*)(gp), \
                                     (__attribute__((address_space(3))) unsigned int*)(lp), 16, 0, 0)

template<int N> __device__ __forceinline__ void vmwait() {
    if constexpr (N == 0)      asm volatile("s_waitcnt vmcnt(0)" ::: "memory");
    else if constexpr (N == 4) asm volatile("s_waitcnt vmcnt(4)" ::: "memory");
    else if constexpr (N == 6) asm volatile("s_waitcnt vmcnt(6)" ::: "memory");
    else static_assert(N == 0, "unsupported vmcnt literal");
}
#define BAR()  __builtin_amdgcn_s_barrier()

// ---------------- cast fp32 -> fp16 ----------------
__global__ __launch_bounds__(256) void cast_all(
    const float* __restrict__ x, const float* __restrict__ wq,
    const float* __restrict__ wk, const float* __restrict__ wv,
    f16* __restrict__ xb, f16* __restrict__ wb)
{
    long i = (long)blockIdx.x * 256 + threadIdx.x;
    const float4* src; f16* dst;
    if (i < 2097152L)            { src = (const float4*)x;  dst = xb; }
    else if (i < 2359296L)       { i -= 2097152L; src = (const float4*)wq; dst = wb; }
    else if (i < 2621440L)       { i -= 2359296L; src = (const float4*)wk; dst = wb + 1048576; }
    else                         { i -= 2621440L; src = (const float4*)wv; dst = wb + 2097152; }
    float4 v = src[i];
    union { f16 h[4]; uint2 u; } o;
    o.h[0] = (f16)v.x; o.h[1] = (f16)v.y; o.h[2] = (f16)v.z; o.h[3] = (f16)v.w;
    ((uint2*)dst)[i] = o.u;
}

// ======== 8-phase 256x256 NT GEMM (verified R6-R8), 512 threads, BK=64 ========
// 8 waves 2(M)x4(N); wave tile 128x64; acc[8][4]. Used for S = Q K^T.
template <typename CT, int TAG>
__global__ __launch_bounds__(512, 2) void gemm8_nt(
    const f16* __restrict__ A, int lda, long sA,
    const f16* __restrict__ B, int ldb, long sB,
    CT* __restrict__ C, int ldc, long sC,
    int K, float alpha)
{
    __shared__ f16 lds[2][32768];   // 128 KiB

    const int tid = threadIdx.x;
    const int m0 = blockIdx.y * 256;
    const int n0 = blockIdx.x * 256;
    const int bz = blockIdx.z;
    A += (long)bz * sA; B += (long)bz * sB; C += (long)bz * sC;

    const int w  = tid >> 6;
    const int l  = tid & 63;
    const int wm = w >> 2;
    const int wn = w & 3;
    const int lr = l & 15;
    const int kg = l >> 4;
    const int kx = kg ^ ((lr >> 1) & 3);

    floatx4 acc[8][4] = {};

    const int srow = tid >> 2;
    const int gsl  = (tid & 3) ^ ((tid >> 3) & 3);
    const long ldaL = lda, ldbL = ldb;
    const f16* Ag = A + (long)(m0 + srow) * ldaL + gsl * 8;
    const f16* Bg = B + (long)(n0 + srow) * ldbL + gsl * 8;

    auto stA = [&](int buf, int h, int t) {
        f16* d = &lds[buf][h * 8192 + w * 512];
        const f16* g = Ag + (long)(h * 128) * ldaL + t * 64;
        ASYNC16(g,      d);
        ASYNC16(g + 32, d + 4096);
    };
    auto stB = [&](int buf, int h, int t) {
        f16* d = &lds[buf][16384 + h * 8192 + w * 512];
        const f16* g = Bg + (long)(h * 128) * ldbL + t * 64;
        ASYNC16(g,      d);
        ASYNC16(g + 32, d + 4096);
    };

    const int NT = K >> 6;
    stA(0, 0, 0); stA(0, 1, 0); stB(0, 0, 0); stB(0, 1, 0);
    stB(1, 0, 1); stB(1, 1, 1);
    vmwait<4>();
    BAR();

    const int abase = wm * 8192;
    const int bbase = 16384 + (wn >> 1) * 8192 + (wn & 1) * 2048;
    f16x8 af[2][4], bf0[2][2], bf1[2][2];

    for (int u = 0; u < NT; ++u) {
        const int cur = u & 1;
        const f16* Lc = lds[cur];

        #pragma unroll
        for (int kk = 0; kk < 2; kk++) {
            #pragma unroll
            for (int mi = 0; mi < 4; mi++)
                af[kk][mi] = *(const f16x8*)&Lc[abase + kk * 4096 + (mi * 16 + lr) * 32 + kx * 8];
            #pragma unroll
            for (int ni = 0; ni < 2; ni++)
                bf0[kk][ni] = *(const f16x8*)&Lc[bbase + kk * 4096 + (ni * 16 + lr) * 32 + kx * 8];
        }
        if (u + 1 < NT) stA(cur ^ 1, 0, u + 1);
        BAR();
        __builtin_amdgcn_s_setprio(1);
        #pragma unroll
        for (int kk = 0; kk < 2; kk++)
            #pragma unroll
            for (int mi = 0; mi < 4; mi++)
                #pragma unroll
                for (int ni = 0; ni < 2; ni++)
                    acc[mi][ni] = __builtin_amdgcn_mfma_f32_16x16x32_f16(af[kk][mi], bf0[kk][ni], acc[mi][ni], 0, 0, 0);
        __builtin_amdgcn_s_setprio(0);
        BAR();

        #pragma unroll
        for (int kk = 0; kk < 2; kk++)
            #pragma unroll
            for (int ni = 0; ni < 2; ni++)
                bf1[kk][ni] = *(const f16x8*)&Lc[bbase + kk * 4096 + ((ni + 2) * 16 + lr) * 32 + kx * 8];
        if (u + 1 < NT) stA(cur ^ 1, 1, u + 1);
        BAR();
        __builtin_amdgcn_s_setprio(1);
        #pragma unroll
        for (int kk = 0; kk < 2; kk++)
            #pragma unroll
            for (int mi = 0; mi < 4; mi++)
                #pragma unroll
                for (int ni = 0; ni < 2; ni++)
                    acc[mi][ni + 2] = __builtin_amdgcn_mfma_f32_16x16x32_f16(af[kk][mi], bf1[kk][ni], acc[mi][ni + 2], 0, 0, 0);
        __builtin_amdgcn_s_setprio(0);
        BAR();

        #pragma unroll
        for (int kk = 0; kk < 2; kk++)
            #pragma unroll
            for (int mi = 0; mi < 4; mi++)
                af[kk][mi] = *(const f16x8*)&Lc[abase + kk * 4096 + ((mi + 4) * 16 + lr) * 32 + kx * 8];
        if (u + 2 < NT) stB(cur, 0, u + 2);
        BAR();
        __builtin_amdgcn_s_setprio(1);
        #pragma unroll
        for (int kk = 0; kk < 2; kk++)
            #pragma unroll
            for (int mi = 0; mi < 4; mi++)
                #pragma unroll
                for (int ni = 0; ni < 2; ni++)
                    acc[mi + 4][ni + 2] = __builtin_amdgcn_mfma_f32_16x16x32_f16(af[kk][mi], bf1[kk][ni], acc[mi + 4][ni + 2], 0, 0, 0);
        __builtin_amdgcn_s_setprio(0);
        BAR();

        if (u + 2 < NT) stB(cur, 1, u + 2);
        BAR();
        __builtin_amdgcn_s_setprio(1);
        #pragma unroll
        for (int kk = 0; kk < 2; kk++)
            #pragma unroll
            for (int mi = 0; mi < 4; mi++)
                #pragma unroll
                for (int ni = 0; ni < 2; ni++)
                    acc[mi + 4][ni] = __builtin_amdgcn_mfma_f32_16x16x32_f16(af[kk][mi], bf0[kk][ni], acc[mi + 4][ni], 0, 0, 0);
        __builtin_amdgcn_s_setprio(0);
        if (u + 2 < NT)      vmwait<4>();
        else if (u + 1 < NT) vmwait<0>();
        BAR();
    }

    #pragma unroll
    for (int mi = 0; mi < 8; mi++)
        #pragma unroll
        for (int ni = 0; ni < 4; ni++)
            #pragma unroll
            for (int r = 0; r < 4; r++) {
                int row = m0 + wm * 128 + mi * 16 + kg * 4 + r;
                int col = n0 + wn * 64 + ni * 16 + lr;
                float v = acc[mi][ni][r] * alpha;
                if constexpr (std::is_same<CT, float>::value)
                    C[(long)row * ldc + col] = v;
                else
                    C[(long)row * ldc + col] = (f16)v;
            }
}

// ======== 8-phase 128x256 NT GEMM (verified R8 as PV), 512 threads, BK=64 ========
// 8 waves 2(M)x4(N); wave tile 64x64; acc[4][4]; LDS 96 KiB.
// VSPLIT (R9, QKV only): column strips n0>=2048 are the Wv rows -> write
//   vt[b][d][j] (d=col-2048, j=row) via packed 8-B stores (r=0..3 are 4
//   consecutive j); Q/K strips write packed qk (ld 2048). Values bit-identical
//   to the old qkv-write + transpose_v path.
template <typename CT, int TAG, bool VSPLIT>
__global__ __launch_bounds__(512, 2) void gemm8b_nt(
    const f16* __restrict__ A, int lda, long sA,
    const f16* __restrict__ B, int ldb, long sB,
    CT* __restrict__ C, int ldc, long sC,
    int K, float alpha, f16* __restrict__ vt)
{
    __shared__ f16 lds[2][24576];   // 96 KiB

    const int tid = threadIdx.x;
    const int m0 = blockIdx.y * 128;
    const int n0 = blockIdx.x * 256;
    const int bz = blockIdx.z;
    A += (long)bz * sA; B += (long)bz * sB; C += (long)bz * sC;

    const int w  = tid >> 6;
    const int l  = tid & 63;
    const int wm = w >> 2;          // 0..1
    const int wn = w & 3;           // 0..3
    const int lr = l & 15;
    const int kg = l >> 4;
    const int kx = kg ^ ((lr >> 1) & 3);

    floatx4 acc[4][4] = {};

    const int srow = tid >> 2;
    const int gsl  = (tid & 3) ^ ((tid >> 3) & 3);
    const long ldaL = lda, ldbL = ldb;
    const f16* Ag = A + (long)(m0 + srow) * ldaL + gsl * 8;
    const f16* Bg = B + (long)(n0 + srow) * ldbL + gsl * 8;

    auto stA = [&](int buf, int kk, int t) {
        ASYNC16(Ag + kk * 32 + t * 64, &lds[buf][kk * 4096 + w * 512]);
    };
    auto stB = [&](int buf, int kk, int t) {
        const f16* g = Bg + kk * 32 + t * 64;
        f16* d = &lds[buf][8192 + kk * 8192 + w * 512];
        ASYNC16(g,              d);
        ASYNC16(g + 128 * ldbL, d + 4096);
    };

    const int NT = K >> 6;
    stA(0, 0, 0); stA(0, 1, 0); stB(0, 0, 0); stB(0, 1, 0);
    stB(1, 0, 1); stB(1, 1, 1);
    vmwait<4>();
    BAR();

    const int arow = wm * 64;
    const int brow = wn * 64;
    f16x8 af0[2][2], af1[2][2], bf0[2][2], bf1[2][2];

    for (int u = 0; u < NT; ++u) {
        const int cur = u & 1;
        const f16* Lc = lds[cur];

        #pragma unroll
        for (int kk = 0; kk < 2; kk++) {
            #pragma unroll
            for (int mi = 0; mi < 2; mi++)
                af0[kk][mi] = *(const f16x8*)&Lc[kk * 4096 + (arow + mi * 16 + lr) * 32 + kx * 8];
            #pragma unroll
            for (int ni = 0; ni < 2; ni++)
                bf0[kk][ni] = *(const f16x8*)&Lc[8192 + kk * 8192 + (brow + ni * 16 + lr) * 32 + kx * 8];
        }
        if (u + 1 < NT) stA(cur ^ 1, 0, u + 1);
        BAR();
        __builtin_amdgcn_s_setprio(1);
        #pragma unroll
        for (int kk = 0; kk < 2; kk++)
            #pragma unroll
            for (int mi = 0; mi < 2; mi++)
                #pragma unroll
                for (int ni = 0; ni < 2; ni++)
                    acc[mi][ni] = __builtin_amdgcn_mfma_f32_16x16x32_f16(af0[kk][mi], bf0[kk][ni], acc[mi][ni], 0, 0, 0);
        __builtin_amdgcn_s_setprio(0);
        BAR();

        #pragma unroll
        for (int kk = 0; kk < 2; kk++)
            #pragma unroll
            for (int ni = 0; ni < 2; ni++)
                bf1[kk][ni] = *(const f16x8*)&Lc[8192 + kk * 8192 + (brow + (ni + 2) * 16 + lr) * 32 + kx * 8];
        if (u + 1 < NT) stA(cur ^ 1, 1, u + 1);
        BAR();
        __builtin_amdgcn_s_setprio(1);
        #pragma unroll
        for (int kk = 0; kk < 2; kk++)
            #pragma unroll
            for (int mi = 0; mi < 2; mi++)
                #pragma unroll
                for (int ni = 0; ni < 2; ni++)
                    acc[mi][ni + 2] = __builtin_amdgcn_mfma_f32_16x16x32_f16(af0[kk][mi], bf1[kk][ni], acc[mi][ni + 2], 0, 0, 0);
        __builtin_amdgcn_s_setprio(0);
        BAR();

        #pragma unroll
        for (int kk = 0; kk < 2; kk++)
            #pragma unroll
            for (int mi = 0; mi < 2; mi++)
                af1[kk][mi] = *(const f16x8*)&Lc[kk * 4096 + (arow + (mi + 2) * 16 + lr) * 32 + kx * 8];
        if (u + 2 < NT) stB(cur, 0, u + 2);
        BAR();
        __builtin_amdgcn_s_setprio(1);
        #pragma unroll
        for (int kk = 0; kk < 2; kk++)
            #pragma unroll
            for (int mi = 0; mi < 2; mi++)
                #pragma unroll
                for (int ni = 0; ni < 2; ni++)
                    acc[mi + 2][ni + 2] = __builtin_amdgcn_mfma_f32_16x16x32_f16(af1[kk][mi], bf1[kk][ni], acc[mi + 2][ni + 2], 0, 0, 0);
        __builtin_amdgcn_s_setprio(0);
        BAR();

        if (u + 2 < NT) stB(cur, 1, u + 2);
        BAR();
        __builtin_amdgcn_s_setprio(1);
        #pragma unroll
        for (int kk = 0; kk < 2; kk++)
            #pragma unroll
            for (int mi = 0; mi < 2; mi++)
                #pragma unroll
                for (int ni = 0; ni < 2; ni++)
                    acc[mi + 2][ni] = __builtin_amdgcn_mfma_f32_16x16x32_f16(af1[kk][mi], bf0[kk][ni], acc[mi + 2][ni], 0, 0, 0);
        __builtin_amdgcn_s_setprio(0);
        if (u + 2 < NT)      vmwait<4>();
        else if (u + 1 < NT) vmwait<0>();
        BAR();
    }

    if (VSPLIT && n0 >= 2048) {
        // V^T role: vt[b][d][j]; b = row>>11, j = row&2047 (128-row tile never
        // crosses a batch boundary: 2048 % 128 == 0). r=0..3 -> j..j+3 packed.
        const int  jj0 = (m0 & 2047) + wm * 64;
        const long bb  = (long)(m0 >> 11) * (1024L * 2048);
        #pragma unroll
        for (int mi = 0; mi < 4; mi++)
            #pragma unroll
            for (int ni = 0; ni < 4; ni++) {
                int d  = (n0 - 2048) + wn * 64 + ni * 16 + lr;
                int jj = jj0 + mi * 16 + kg * 4;
                union { f16 h[4]; uint2 u; } o;
                #pragma unroll
                for (int r = 0; r < 4; r++) o.h[r] = (f16)(acc[mi][ni][r] * alpha);
                *(uint2*)&vt[bb + (long)d * 2048 + jj] = o.u;
            }
    } else {
        #pragma unroll
        for (int mi = 0; mi < 4; mi++)
            #pragma unroll
            for (int ni = 0; ni < 4; ni++)
                #pragma unroll
                for (int r = 0; r < 4; r++) {
                    int row = m0 + wm * 64 + mi * 16 + kg * 4 + r;
                    int col = n0 + wn * 64 + ni * 16 + lr;
                    float v = acc[mi][ni][r] * alpha;
                    if constexpr (std::is_same<CT, float>::value)
                        C[(long)row * ldc + col] = v;
                    else
                        C[(long)row * ldc + col] = (f16)v;
                }
    }
}

// ---------------- row softmax ----------------
__global__ __launch_bounds__(256) void softmax_rows(f16* __restrict__ S)
{
    long row = (long)blockIdx.x * 4 + (threadIdx.x >> 6);
    int l = threadIdx.x & 63;
    uint4* p4 = (uint4*)(S + row * 2048);
    union U { uint4 u; f16 h[8]; } d[4];
    float v[32];
    float mx = -1e30f;
    #pragma unroll
    for (int i = 0; i < 4; i++) {
        d[i].u = p4[i * 64 + l];
        #pragma unroll
        for (int j = 0; j < 8; j++) { v[i * 8 + j] = (float)d[i].h[j]; mx = fmaxf(mx, v[i * 8 + j]); }
    }
    #pragma unroll
    for (int off = 32; off; off >>= 1) mx = fmaxf(mx, __shfl_xor(mx, off, 64));
    float s = 0.f;
    #pragma unroll
    for (int i = 0; i < 32; i++) { v[i] = __expf(v[i] - mx); s += v[i]; }
    #pragma unroll
    for (int off = 32; off; off >>= 1) s += __shfl_xor(s, off, 64);
    float inv = 1.f / s;
    #pragma unroll
    for (int i = 0; i < 4; i++) {
        #pragma unroll
        for (int j = 0; j < 8; j++) d[i].h[j] = (f16)(v[i * 8 + j] * inv);
        p4[i * 64 + l] = d[i].u;
    }
}

// ---------------- launch ----------------
extern "C" void kernel_launch(void* const* d_in, const int* in_sizes, int n_in,
                              void* d_out, int out_size, void* d_ws, size_t ws_size,
                              hipStream_t stream)
{
    const float* x  = (const float*)d_in[0];
    const float* wq = (const float*)d_in[1];
    const float* wk = (const float*)d_in[2];
    const float* wv = (const float*)d_in[3];
    float* out = (float*)d_out;
    char* ws = (char*)d_ws;
    f16* xb = (f16*)(ws + XB_OFF);
    f16* wb = (f16*)(ws + WB_OFF);
    f16* qk = (f16*)(ws + QK_OFF);
    f16* vt = (f16*)(ws + VT_OFF);
    f16* s  = (f16*)(ws + S_OFF);

    // 1) cast
    cast_all<<<11264, 256, 0, stream>>>(x, wq, wk, wv, xb, wb);

    // 2) QKV = xb @ Wb^T : M=8192, N=3072, K=1024 (128x256 8-phase, 768 blocks
    //    = exactly 3 rounds). Strips 0..7 -> packed qk (ld 2048); strips 8..11
    //    (Wv) -> vt directly (transpose fused, transpose_v kernel deleted).
    gemm8b_nt<f16, 0, true><<<dim3(12, 64, 1), 512, 0, stream>>>(
        xb, 1024, 0L, wb, 1024, 0L, qk, 2048, 0L, 1024, 1.0f, vt);

    // 3) S = (1/32) Q @ K^T per batch : M=N=2048, K=1024 (256^2 8-phase)
    gemm8_nt<f16, 1><<<dim3(8, 8, 4), 512, 0, stream>>>(
        qk,        2048, (long)T_ * 2048,
        qk + 1024, 2048, (long)T_ * 2048,
        s,         2048, (long)T_ * 2048, 1024, 0.03125f);

    // 4) softmax rows, in place
    softmax_rows<<<2048, 256, 0, stream>>>(s);

    // 5) O = P @ Vt^T per batch : M=2048, N=1024, K=2048 (128x256 8-phase,
    //    256 blocks exactly)
    gemm8b_nt<float, 1, false><<<dim3(4, 16, 4), 512, 0, stream>>>(
        s,  2048, (long)T_ * 2048,
        vt, 2048, (long)D_ * 2048,
        out, 1024, (long)T_ * 1024, 2048, 1.0f, nullptr);
}

// Round 12
// 251.271 us; speedup vs baseline: 1.0626x; 1.0008x over previous
//
#include <hip/hip_runtime.h>
#include <hip/hip_bf16.h>
#include <hip/hip_fp16.h>
#include <type_traits>

typedef _Float16 f16;
typedef __attribute__((ext_vector_type(8))) _Float16 f16x8;
typedef __attribute__((ext_vector_type(4))) float floatx4;

#define B_ 4
#define T_ 2048
#define D_ 1024

// ws layout (bytes); total = 106,954,752
#define XB_OFF   0ul          // f16 x: 16 MB
#define WB_OFF   16777216ul   // f16 [Wq;Wk;Wv] 3072x1024: 6 MB
#define QK_OFF   23068672ul   // f16 qk (8192x2048 packed Q|K): 32 MB
#define VT_OFF   56623104ul   // f16 vt (4x1024x2048): 16 MB
#define S_OFF    73400320ul   // f16 S (4x2048x2048): 32 MB

// async global->LDS, 16B per lane; lds dest = wave-uniform base + lane*16
#define ASYNC16(gp, lp) \
    __builtin_amdgcn_global_load_lds((const __attribute__((address_space(1))) unsigned int*)(gp), \
                                     (__attribute__((address_space(3))) unsigned int*)(lp), 16, 0, 0)

template<int N> __device__ __forceinline__ void vmwait() {
    if constexpr (N == 0)      asm volatile("s_waitcnt vmcnt(0)" ::: "memory");
    else if constexpr (N == 4) asm volatile("s_waitcnt vmcnt(4)" ::: "memory");
    else if constexpr (N == 6) asm volatile("s_waitcnt vmcnt(6)" ::: "memory");
    else static_assert(N == 0, "unsupported vmcnt literal");
}
#define BAR()  __builtin_amdgcn_s_barrier()

// ---------------- cast fp32 -> fp16 ----------------
__global__ __launch_bounds__(256) void cast_all(
    const float* __restrict__ x, const float* __restrict__ wq,
    const float* __restrict__ wk, const float* __restrict__ wv,
    f16* __restrict__ xb, f16* __restrict__ wb)
{
    long i = (long)blockIdx.x * 256 + threadIdx.x;
    const float4* src; f16* dst;
    if (i < 2097152L)            { src = (const float4*)x;  dst = xb; }
    else if (i < 2359296L)       { i -= 2097152L; src = (const float4*)wq; dst = wb; }
    else if (i < 2621440L)       { i -= 2359296L; src = (const float4*)wk; dst = wb + 1048576; }
    else                         { i -= 2621440L; src = (const float4*)wv; dst = wb + 2097152; }
    float4 v = src[i];
    union { f16 h[4]; uint2 u; } o;
    o.h[0] = (f16)v.x; o.h[1] = (f16)v.y; o.h[2] = (f16)v.z; o.h[3] = (f16)v.w;
    ((uint2*)dst)[i] = o.u;
}

// ======== 8-phase 256x256 NT GEMM (verified R6-R9) — used for S ========
template <typename CT, int TAG>
__global__ __launch_bounds__(512, 2) void gemm8_nt(
    const f16* __restrict__ A, int lda, long sA,
    const f16* __restrict__ B, int ldb, long sB,
    CT* __restrict__ C, int ldc, long sC,
    int K, float alpha)
{
    __shared__ f16 lds[2][32768];   // 128 KiB

    const int tid = threadIdx.x;
    const int m0 = blockIdx.y * 256;
    const int n0 = blockIdx.x * 256;
    const int bz = blockIdx.z;
    A += (long)bz * sA; B += (long)bz * sB; C += (long)bz * sC;

    const int w  = tid >> 6;
    const int l  = tid & 63;
    const int wm = w >> 2;
    const int wn = w & 3;
    const int lr = l & 15;
    const int kg = l >> 4;
    const int kx = kg ^ ((lr >> 1) & 3);

    floatx4 acc[8][4] = {};

    const int srow = tid >> 2;
    const int gsl  = (tid & 3) ^ ((tid >> 3) & 3);
    const long ldaL = lda, ldbL = ldb;
    const f16* Ag = A + (long)(m0 + srow) * ldaL + gsl * 8;
    const f16* Bg = B + (long)(n0 + srow) * ldbL + gsl * 8;

    auto stA = [&](int buf, int h, int t) {
        f16* d = &lds[buf][h * 8192 + w * 512];
        const f16* g = Ag + (long)(h * 128) * ldaL + t * 64;
        ASYNC16(g,      d);
        ASYNC16(g + 32, d + 4096);
    };
    auto stB = [&](int buf, int h, int t) {
        f16* d = &lds[buf][16384 + h * 8192 + w * 512];
        const f16* g = Bg + (long)(h * 128) * ldbL + t * 64;
        ASYNC16(g,      d);
        ASYNC16(g + 32, d + 4096);
    };

    const int NT = K >> 6;
    stA(0, 0, 0); stA(0, 1, 0); stB(0, 0, 0); stB(0, 1, 0);
    stB(1, 0, 1); stB(1, 1, 1);
    vmwait<4>();
    BAR();

    const int abase = wm * 8192;
    const int bbase = 16384 + (wn >> 1) * 8192 + (wn & 1) * 2048;
    f16x8 af[2][4], bf0[2][2], bf1[2][2];

    for (int u = 0; u < NT; ++u) {
        const int cur = u & 1;
        const f16* Lc = lds[cur];

        #pragma unroll
        for (int kk = 0; kk < 2; kk++) {
            #pragma unroll
            for (int mi = 0; mi < 4; mi++)
                af[kk][mi] = *(const f16x8*)&Lc[abase + kk * 4096 + (mi * 16 + lr) * 32 + kx * 8];
            #pragma unroll
            for (int ni = 0; ni < 2; ni++)
                bf0[kk][ni] = *(const f16x8*)&Lc[bbase + kk * 4096 + (ni * 16 + lr) * 32 + kx * 8];
        }
        if (u + 1 < NT) stA(cur ^ 1, 0, u + 1);
        BAR();
        __builtin_amdgcn_s_setprio(1);
        #pragma unroll
        for (int kk = 0; kk < 2; kk++)
            #pragma unroll
            for (int mi = 0; mi < 4; mi++)
                #pragma unroll
                for (int ni = 0; ni < 2; ni++)
                    acc[mi][ni] = __builtin_amdgcn_mfma_f32_16x16x32_f16(af[kk][mi], bf0[kk][ni], acc[mi][ni], 0, 0, 0);
        __builtin_amdgcn_s_setprio(0);
        BAR();

        #pragma unroll
        for (int kk = 0; kk < 2; kk++)
            #pragma unroll
            for (int ni = 0; ni < 2; ni++)
                bf1[kk][ni] = *(const f16x8*)&Lc[bbase + kk * 4096 + ((ni + 2) * 16 + lr) * 32 + kx * 8];
        if (u + 1 < NT) stA(cur ^ 1, 1, u + 1);
        BAR();
        __builtin_amdgcn_s_setprio(1);
        #pragma unroll
        for (int kk = 0; kk < 2; kk++)
            #pragma unroll
            for (int mi = 0; mi < 4; mi++)
                #pragma unroll
                for (int ni = 0; ni < 2; ni++)
                    acc[mi][ni + 2] = __builtin_amdgcn_mfma_f32_16x16x32_f16(af[kk][mi], bf1[kk][ni], acc[mi][ni + 2], 0, 0, 0);
        __builtin_amdgcn_s_setprio(0);
        BAR();

        #pragma unroll
        for (int kk = 0; kk < 2; kk++)
            #pragma unroll
            for (int mi = 0; mi < 4; mi++)
                af[kk][mi] = *(const f16x8*)&Lc[abase + kk * 4096 + ((mi + 4) * 16 + lr) * 32 + kx * 8];
        if (u + 2 < NT) stB(cur, 0, u + 2);
        BAR();
        __builtin_amdgcn_s_setprio(1);
        #pragma unroll
        for (int kk = 0; kk < 2; kk++)
            #pragma unroll
            for (int mi = 0; mi < 4; mi++)
                #pragma unroll
                for (int ni = 0; ni < 2; ni++)
                    acc[mi + 4][ni + 2] = __builtin_amdgcn_mfma_f32_16x16x32_f16(af[kk][mi], bf1[kk][ni], acc[mi + 4][ni + 2], 0, 0, 0);
        __builtin_amdgcn_s_setprio(0);
        BAR();

        if (u + 2 < NT) stB(cur, 1, u + 2);
        BAR();
        __builtin_amdgcn_s_setprio(1);
        #pragma unroll
        for (int kk = 0; kk < 2; kk++)
            #pragma unroll
            for (int mi = 0; mi < 4; mi++)
                #pragma unroll
                for (int ni = 0; ni < 2; ni++)
                    acc[mi + 4][ni] = __builtin_amdgcn_mfma_f32_16x16x32_f16(af[kk][mi], bf0[kk][ni], acc[mi + 4][ni], 0, 0, 0);
        __builtin_amdgcn_s_setprio(0);
        if (u + 2 < NT)      vmwait<4>();
        else if (u + 1 < NT) vmwait<0>();
        BAR();
    }

    #pragma unroll
    for (int mi = 0; mi < 8; mi++)
        #pragma unroll
        for (int ni = 0; ni < 4; ni++)
            #pragma unroll
            for (int r = 0; r < 4; r++) {
                int row = m0 + wm * 128 + mi * 16 + kg * 4 + r;
                int col = n0 + wn * 64 + ni * 16 + lr;
                float v = acc[mi][ni][r] * alpha;
                if constexpr (std::is_same<CT, float>::value)
                    C[(long)row * ldc + col] = v;
                else
                    C[(long)row * ldc + col] = (f16)v;
            }
}

// ======== 8-phase 128x256 NT GEMM (verified R8/R9), 512 threads, BK=64 ========
// VSPLIT (QKV only): column strips n0>=2048 are the Wv rows -> write
//   vt[b][d][j] via packed 8-B stores; Q/K strips write packed qk (ld 2048).
template <typename CT, int TAG, bool VSPLIT>
__global__ __launch_bounds__(512, 2) void gemm8b_nt(
    const f16* __restrict__ A, int lda, long sA,
    const f16* __restrict__ B, int ldb, long sB,
    CT* __restrict__ C, int ldc, long sC,
    int K, float alpha, f16* __restrict__ vt)
{
    __shared__ f16 lds[2][24576];   // 96 KiB

    const int tid = threadIdx.x;
    const int m0 = blockIdx.y * 128;
    const int n0 = blockIdx.x * 256;
    const int bz = blockIdx.z;
    A += (long)bz * sA; B += (long)bz * sB; C += (long)bz * sC;

    const int w  = tid >> 6;
    const int l  = tid & 63;
    const int wm = w >> 2;          // 0..1
    const int wn = w & 3;           // 0..3
    const int lr = l & 15;
    const int kg = l >> 4;
    const int kx = kg ^ ((lr >> 1) & 3);

    floatx4 acc[4][4] = {};

    const int srow = tid >> 2;
    const int gsl  = (tid & 3) ^ ((tid >> 3) & 3);
    const long ldaL = lda, ldbL = ldb;
    const f16* Ag = A + (long)(m0 + srow) * ldaL + gsl * 8;
    const f16* Bg = B + (long)(n0 + srow) * ldbL + gsl * 8;

    auto stA = [&](int buf, int kk, int t) {
        ASYNC16(Ag + kk * 32 + t * 64, &lds[buf][kk * 4096 + w * 512]);
    };
    auto stB = [&](int buf, int kk, int t) {
        const f16* g = Bg + kk * 32 + t * 64;
        f16* d = &lds[buf][8192 + kk * 8192 + w * 512];
        ASYNC16(g,              d);
        ASYNC16(g + 128 * ldbL, d + 4096);
    };

    const int NT = K >> 6;
    stA(0, 0, 0); stA(0, 1, 0); stB(0, 0, 0); stB(0, 1, 0);
    stB(1, 0, 1); stB(1, 1, 1);
    vmwait<4>();
    BAR();

    const int arow = wm * 64;
    const int brow = wn * 64;
    f16x8 af0[2][2], af1[2][2], bf0[2][2], bf1[2][2];

    for (int u = 0; u < NT; ++u) {
        const int cur = u & 1;
        const f16* Lc = lds[cur];

        #pragma unroll
        for (int kk = 0; kk < 2; kk++) {
            #pragma unroll
            for (int mi = 0; mi < 2; mi++)
                af0[kk][mi] = *(const f16x8*)&Lc[kk * 4096 + (arow + mi * 16 + lr) * 32 + kx * 8];
            #pragma unroll
            for (int ni = 0; ni < 2; ni++)
                bf0[kk][ni] = *(const f16x8*)&Lc[8192 + kk * 8192 + (brow + ni * 16 + lr) * 32 + kx * 8];
        }
        if (u + 1 < NT) stA(cur ^ 1, 0, u + 1);
        BAR();
        __builtin_amdgcn_s_setprio(1);
        #pragma unroll
        for (int kk = 0; kk < 2; kk++)
            #pragma unroll
            for (int mi = 0; mi < 2; mi++)
                #pragma unroll
                for (int ni = 0; ni < 2; ni++)
                    acc[mi][ni] = __builtin_amdgcn_mfma_f32_16x16x32_f16(af0[kk][mi], bf0[kk][ni], acc[mi][ni], 0, 0, 0);
        __builtin_amdgcn_s_setprio(0);
        BAR();

        #pragma unroll
        for (int kk = 0; kk < 2; kk++)
            #pragma unroll
            for (int ni = 0; ni < 2; ni++)
                bf1[kk][ni] = *(const f16x8*)&Lc[8192 + kk * 8192 + (brow + (ni + 2) * 16 + lr) * 32 + kx * 8];
        if (u + 1 < NT) stA(cur ^ 1, 1, u + 1);
        BAR();
        __builtin_amdgcn_s_setprio(1);
        #pragma unroll
        for (int kk = 0; kk < 2; kk++)
            #pragma unroll
            for (int mi = 0; mi < 2; mi++)
                #pragma unroll
                for (int ni = 0; ni < 2; ni++)
                    acc[mi][ni + 2] = __builtin_amdgcn_mfma_f32_16x16x32_f16(af0[kk][mi], bf1[kk][ni], acc[mi][ni + 2], 0, 0, 0);
        __builtin_amdgcn_s_setprio(0);
        BAR();

        #pragma unroll
        for (int kk = 0; kk < 2; kk++)
            #pragma unroll
            for (int mi = 0; mi < 2; mi++)
                af1[kk][mi] = *(const f16x8*)&Lc[kk * 4096 + (arow + (mi + 2) * 16 + lr) * 32 + kx * 8];
        if (u + 2 < NT) stB(cur, 0, u + 2);
        BAR();
        __builtin_amdgcn_s_setprio(1);
        #pragma unroll
        for (int kk = 0; kk < 2; kk++)
            #pragma unroll
            for (int mi = 0; mi < 2; mi++)
                #pragma unroll
                for (int ni = 0; ni < 2; ni++)
                    acc[mi + 2][ni + 2] = __builtin_amdgcn_mfma_f32_16x16x32_f16(af1[kk][mi], bf1[kk][ni], acc[mi + 2][ni + 2], 0, 0, 0);
        __builtin_amdgcn_s_setprio(0);
        BAR();

        if (u + 2 < NT) stB(cur, 1, u + 2);
        BAR();
        __builtin_amdgcn_s_setprio(1);
        #pragma unroll
        for (int kk = 0; kk < 2; kk++)
            #pragma unroll
            for (int mi = 0; mi < 2; mi++)
                #pragma unroll
                for (int ni = 0; ni < 2; ni++)
                    acc[mi + 2][ni] = __builtin_amdgcn_mfma_f32_16x16x32_f16(af1[kk][mi], bf0[kk][ni], acc[mi + 2][ni], 0, 0, 0);
        __builtin_amdgcn_s_setprio(0);
        if (u + 2 < NT)      vmwait<4>();
        else if (u + 1 < NT) vmwait<0>();
        BAR();
    }

    if (VSPLIT && n0 >= 2048) {
        // V^T role: vt[b][d][j]; 128-row tile never crosses batch (2048%128==0)
        const int  jj0 = (m0 & 2047) + wm * 64;
        const long bb  = (long)(m0 >> 11) * (1024L * 2048);
        #pragma unroll
        for (int mi = 0; mi < 4; mi++)
            #pragma unroll
            for (int ni = 0; ni < 4; ni++) {
                int d  = (n0 - 2048) + wn * 64 + ni * 16 + lr;
                int jj = jj0 + mi * 16 + kg * 4;
                union { f16 h[4]; uint2 u; } o;
                #pragma unroll
                for (int r = 0; r < 4; r++) o.h[r] = (f16)(acc[mi][ni][r] * alpha);
                *(uint2*)&vt[bb + (long)d * 2048 + jj] = o.u;
            }
    } else {
        #pragma unroll
        for (int mi = 0; mi < 4; mi++)
            #pragma unroll
            for (int ni = 0; ni < 4; ni++)
                #pragma unroll
                for (int r = 0; r < 4; r++) {
                    int row = m0 + wm * 64 + mi * 16 + kg * 4 + r;
                    int col = n0 + wn * 64 + ni * 16 + lr;
                    float v = acc[mi][ni][r] * alpha;
                    if constexpr (std::is_same<CT, float>::value)
                        C[(long)row * ldc + col] = v;
                    else
                        C[(long)row * ldc + col] = (f16)v;
                }
    }
}

// ---------------- row softmax ----------------
__global__ __launch_bounds__(256) void softmax_rows(f16* __restrict__ S)
{
    long row = (long)blockIdx.x * 4 + (threadIdx.x >> 6);
    int l = threadIdx.x & 63;
    uint4* p4 = (uint4*)(S + row * 2048);
    union U { uint4 u; f16 h[8]; } d[4];
    float v[32];
    float mx = -1e30f;
    #pragma unroll
    for (int i = 0; i < 4; i++) {
        d[i].u = p4[i * 64 + l];
        #pragma unroll
        for (int j = 0; j < 8; j++) { v[i * 8 + j] = (float)d[i].h[j]; mx = fmaxf(mx, v[i * 8 + j]); }
    }
    #pragma unroll
    for (int off = 32; off; off >>= 1) mx = fmaxf(mx, __shfl_xor(mx, off, 64));
    float s = 0.f;
    #pragma unroll
    for (int i = 0; i < 32; i++) { v[i] = __expf(v[i] - mx); s += v[i]; }
    #pragma unroll
    for (int off = 32; off; off >>= 1) s += __shfl_xor(s, off, 64);
    float inv = 1.f / s;
    #pragma unroll
    for (int i = 0; i < 4; i++) {
        #pragma unroll
        for (int j = 0; j < 8; j++) d[i].h[j] = (f16)(v[i * 8 + j] * inv);
        p4[i * 64 + l] = d[i].u;
    }
}

// ---------------- launch ----------------
extern "C" void kernel_launch(void* const* d_in, const int* in_sizes, int n_in,
                              void* d_out, int out_size, void* d_ws, size_t ws_size,
                              hipStream_t stream)
{
    const float* x  = (const float*)d_in[0];
    const float* wq = (const float*)d_in[1];
    const float* wk = (const float*)d_in[2];
    const float* wv = (const float*)d_in[3];
    float* out = (float*)d_out;
    char* ws = (char*)d_ws;
    f16* xb = (f16*)(ws + XB_OFF);
    f16* wb = (f16*)(ws + WB_OFF);
    f16* qk = (f16*)(ws + QK_OFF);
    f16* vt = (f16*)(ws + VT_OFF);
    f16* s  = (f16*)(ws + S_OFF);

    // 1) cast
    cast_all<<<11264, 256, 0, stream>>>(x, wq, wk, wv, xb, wb);

    // 2) QKV = xb @ Wb^T : M=8192, N=3072, K=1024 (128x256 8-phase, 768 blocks
    //    = exactly 3 rounds). Strips 0..7 -> packed qk (ld 2048); strips 8..11
    //    (Wv) -> vt directly (transpose fused).
    gemm8b_nt<f16, 0, true><<<dim3(12, 64, 1), 512, 0, stream>>>(
        xb, 1024, 0L, wb, 1024, 0L, qk, 2048, 0L, 1024, 1.0f, vt);

    // 3) S = (1/32) Q @ K^T per batch : M=N=2048, K=1024 (256^2 8-phase)
    gemm8_nt<f16, 1><<<dim3(8, 8, 4), 512, 0, stream>>>(
        qk,        2048, (long)T_ * 2048,
        qk + 1024, 2048, (long)T_ * 2048,
        s,         2048, (long)T_ * 2048, 1024, 0.03125f);

    // 4) softmax rows, in place
    softmax_rows<<<2048, 256, 0, stream>>>(s);

    // 5) O = P @ Vt^T per batch : M=2048, N=1024, K=2048 (128x256 8-phase,
    //    256 blocks exactly)
    gemm8b_nt<float, 1, false><<<dim3(4, 16, 4), 512, 0, stream>>>(
        s,  2048, (long)T_ * 2048,
        vt, 2048, (long)D_ * 2048,
        out, 1024, (long)T_ * 1024, 2048, 1.0f, nullptr);
}